// Round 3
// baseline (617.944 us; speedup 1.0000x reference)
//
#include <hip/hip_runtime.h>
#include <stdint.h>

typedef __attribute__((ext_vector_type(8))) short short8;
typedef __attribute__((ext_vector_type(4))) float floatx4;

// ---------- helpers ----------
__device__ __forceinline__ unsigned short f2b(float f) {
    union { float f; uint32_t u; } v; v.f = f;
    uint32_t u = v.u;
    return (unsigned short)((u + 0x7FFFu + ((u >> 16) & 1u)) >> 16);  // RNE
}

// pack two fp32 -> two bf16 (round-half-up; plenty of margin vs threshold)
__device__ __forceinline__ uint32_t pk2(float a, float b) {
    union { float f; uint32_t u; } x, y; x.f = a; y.f = b;
    uint32_t ua = x.u + 0x8000u, ub = y.u + 0x8000u;
    return (ua >> 16) | (ub & 0xFFFF0000u);
}

// ---------- kernel 1: L2-normalize rows, emit bf16; also zero S ----------
__global__ void norm_kernel(const float* __restrict__ in,
                            unsigned short* __restrict__ xb,
                            float* __restrict__ S, int D) {
    int b = blockIdx.x, t = threadIdx.x;
    if (t == 0) S[b] = 0.f;                     // replaces hipMemsetAsync
    const float* row = in + (size_t)b * D;
    float ss = 0.f;
    for (int i = t * 4; i < D; i += 1024) {
        float4 v = *(const float4*)(row + i);
        ss += v.x * v.x + v.y * v.y + v.z * v.z + v.w * v.w;
    }
    for (int off = 32; off > 0; off >>= 1) ss += __shfl_down(ss, off);
    __shared__ float wsum[4];
    __shared__ float rn_sh;
    if ((t & 63) == 0) wsum[t >> 6] = ss;
    __syncthreads();
    if (t == 0) rn_sh = rsqrtf(wsum[0] + wsum[1] + wsum[2] + wsum[3]);
    __syncthreads();
    float rn = rn_sh;
    unsigned short* orow = xb + (size_t)b * D;
    for (int i = t * 4; i < D; i += 1024) {
        float4 v = *(const float4*)(row + i);
        ushort4 o;
        o.x = f2b(v.x * rn); o.y = f2b(v.y * rn);
        o.z = f2b(v.z * rn); o.w = f2b(v.w * rn);
        *(ushort4*)(orow + i) = o;
    }
}

// ---------- kernel 2: fused GEMM, software-pipelined ----------
// BM=256 (full batch), BN=64, BK=64.  A: direct global->VGPR (xb is 1 MB,
// L2-resident; loads are in exact MFMA A-layout).  B: fp32 global->regs with
// prefetch distance 2, cvt->bf16 ds_write into double-buffered LDS.  The
// compiler's vmcnt(0) drain at each __syncthreads only waits on loads issued
// a full compute-phase earlier -> latency hidden.
// Blds layout: row r (128 B), 16 B chunk c stored at slot c^(r&7): all b128
// read/write phases <=2-way (conflict-free, verified R2).
__global__ __launch_bounds__(256)
void gemm_kernel(const unsigned short* __restrict__ xb,
                 const float* __restrict__ featB,
                 const float* __restrict__ centB,
                 const int* __restrict__ targets,
                 float* __restrict__ S, float* __restrict__ pos,
                 float* __restrict__ km,
                 int D, int K, int nbF) {
    __shared__ __align__(16) unsigned short Blds[2][64 * 64];  // 2 x 8 KB

    const int t = threadIdx.x;
    const int w = t >> 6, l = t & 63;
    const bool isFeat = ((int)blockIdx.x < nbF);
    const int n0 = (isFeat ? (int)blockIdx.x : ((int)blockIdx.x - nbF)) * 64;
    const float* Bsrc = isFeat ? featB : centB;

    floatx4 acc[4][4];
#pragma unroll
    for (int ti = 0; ti < 4; ++ti)
#pragma unroll
        for (int tj = 0; tj < 4; ++tj)
            acc[ti][tj] = (floatx4){0.f, 0.f, 0.f, 0.f};

    const int kIters = D / 64;                        // 32
    const int brow = t >> 2, bq = t & 3;              // B staging: 4 thr/row
    const float* bg0 = Bsrc + (size_t)(n0 + brow) * D + bq * 16;
    const int bs0 = ((bq * 2) ^ (brow & 7)) * 16;     // swizzled chunk slots
    const int bs1 = ((bq * 2 + 1) ^ (brow & 7)) * 16;
    const char* xbB = (const char*)xb;

    float4 rA[4], rB[4];
    auto loadB = [&](int kt, float4* r) {
        const float* p = bg0 + kt * 64;
        r[0] = *(const float4*)(p);
        r[1] = *(const float4*)(p + 4);
        r[2] = *(const float4*)(p + 8);
        r[3] = *(const float4*)(p + 12);
    };
    auto cvtW = [&](const float4* r, int buf) {
        uint4 p0, p1;
        p0.x = pk2(r[0].x, r[0].y); p0.y = pk2(r[0].z, r[0].w);
        p0.z = pk2(r[1].x, r[1].y); p0.w = pk2(r[1].z, r[1].w);
        p1.x = pk2(r[2].x, r[2].y); p1.y = pk2(r[2].z, r[2].w);
        p1.z = pk2(r[3].x, r[3].y); p1.w = pk2(r[3].z, r[3].w);
        char* bb = (char*)&Blds[buf][0] + brow * 128;
        *(uint4*)(bb + bs0) = p0;
        *(uint4*)(bb + bs1) = p1;
    };
    auto compute = [&](int buf, int kt) {
        short8 aF[2][4];
#pragma unroll
        for (int s2 = 0; s2 < 2; ++s2)
#pragma unroll
            for (int ti = 0; ti < 4; ++ti) {
                int R = w * 64 + ti * 16 + (l & 15);
                aF[s2][ti] = *(const short8*)(xbB + (size_t)R * (D * 2) +
                              kt * 128 + (s2 * 4 + (l >> 4)) * 16);
            }
#pragma unroll
        for (int s2 = 0; s2 < 2; ++s2) {
            short8 bF[4];
#pragma unroll
            for (int tj = 0; tj < 4; ++tj) {
                int Rn = tj * 16 + (l & 15);
                int g = s2 * 4 + (l >> 4);
                bF[tj] = *(const short8*)((const char*)&Blds[buf][0] +
                          Rn * 128 + ((g ^ (Rn & 7)) * 16));
            }
#pragma unroll
            for (int ti = 0; ti < 4; ++ti)
#pragma unroll
                for (int tj = 0; tj < 4; ++tj)
                    acc[ti][tj] = __builtin_amdgcn_mfma_f32_16x16x32_bf16(
                        aF[s2][ti], bF[tj], acc[ti][tj], 0, 0, 0);
        }
    };

    // pipeline prologue
    loadB(0, rA);
    loadB(1, rB);
    cvtW(rA, 0);
    __syncthreads();

#pragma unroll 1
    for (int kt = 0; kt < kIters; kt += 2) {
        // even: compute tile kt from buf0; stage B(kt+1)->buf1; fetch B(kt+2)
        if (kt + 2 < kIters) loadB(kt + 2, rA);
        cvtW(rB, 1);                                  // rB = B(kt+1), loaded 1 iter ago
        compute(0, kt);
        __syncthreads();
        // odd: compute tile kt+1 from buf1; stage B(kt+2)->buf0; fetch B(kt+3)
        if (kt + 3 < kIters) loadB(kt + 3, rB);
        if (kt + 2 < kIters) cvtW(rA, 0);             // rA = B(kt+2)
        compute(1, kt + 1);
        __syncthreads();
    }

    // epilogue.  C/D layout: col = l&15, row = (l>>4)*4 + reg  [m89-verified]
    if (isFeat) {
#pragma unroll
        for (int ti = 0; ti < 4; ++ti) {
#pragma unroll
            for (int r = 0; r < 4; ++r) {
                int row = w * 64 + ti * 16 + ((l >> 4) << 2) + r;
                int tr = targets[row];
                int col0 = n0 + (l & 15);
                float e = 0.f;
#pragma unroll
                for (int tj = 0; tj < 4; ++tj) {
                    float c = acc[ti][tj][r];
                    e += __expf(c * 20.0f);            // |c|<=~1 -> safe
                    if (tr == col0 + tj * 16) pos[row] = c;
                }
                e += __shfl_xor(e, 1); e += __shfl_xor(e, 2);
                e += __shfl_xor(e, 4); e += __shfl_xor(e, 8);
                if ((l & 15) == 0) atomicAdd(&S[row], e);
            }
        }
    } else {
#pragma unroll
        for (int ti = 0; ti < 4; ++ti) {
#pragma unroll
            for (int r = 0; r < 4; ++r) {
                int row = w * 64 + ti * 16 + ((l >> 4) << 2) + r;
                size_t base = (size_t)row * K + n0 + (l & 15);
#pragma unroll
                for (int tj = 0; tj < 4; ++tj)
                    km[base + tj * 16] = acc[ti][tj][r];
            }
        }
    }
}

// ---------- kernel 3: per-row top-neg_size (register-resident selection) ----
__global__ __launch_bounds__(256, 4)
void topk_kernel(const float* __restrict__ kmr,
                 const int* __restrict__ pids,
                 const int* __restrict__ idxs,
                 const int* __restrict__ negsz,
                 float* __restrict__ topv, int K) {
    int b = blockIdx.x, t = threadIdx.x;
    int w = t >> 6, l = t & 63;
    const float* row = kmr + (size_t)b * K;
    float v[32];
#pragma unroll
    for (int k = 0; k < 32; ++k) v[k] = row[k * 256 + t];
    int gi = pids[idxs[b]];          // masked position (never top-20 in ref)
    if ((gi & 255) == t) {
        int kk = gi >> 8;
#pragma unroll
        for (int k = 0; k < 32; ++k) if (k == kk) v[k] = -1e30f;
    }
    float bv = v[0]; int bk = 0;
#pragma unroll
    for (int k = 1; k < 32; ++k) if (v[k] > bv) { bv = v[k]; bk = k; }

    __shared__ float rv[4];
    __shared__ int rg[4];
    int ns = *negsz; if (ns > 32) ns = 32;
    for (int j = 0; j < ns; ++j) {
        float mv = bv; int mg = bk * 256 + t;
#pragma unroll
        for (int off = 1; off < 64; off <<= 1) {
            float ov = __shfl_xor(mv, off);
            int og = __shfl_xor(mg, off);
            if (ov > mv) { mv = ov; mg = og; }
        }
        if (l == 0) { rv[w] = mv; rg[w] = mg; }
        __syncthreads();
        float gv = rv[0]; int gg = rg[0];
#pragma unroll
        for (int ww = 1; ww < 4; ++ww)
            if (rv[ww] > gv) { gv = rv[ww]; gg = rg[ww]; }
        if (t == 0) topv[b * 32 + j] = gv;
        if ((gg & 255) == t) {
            int kk = gg >> 8;
#pragma unroll
            for (int k = 0; k < 32; ++k) if (k == kk) v[k] = -1e30f;
            bv = v[0]; bk = 0;
#pragma unroll
            for (int k = 1; k < 32; ++k) if (v[k] > bv) { bv = v[k]; bk = k; }
        }
        __syncthreads();
    }
}

// ---------- kernel 4: confidence mask + losses + final scalar ----------
__global__ void final_kernel(const float* __restrict__ S,
                             const float* __restrict__ pos,
                             const float* __restrict__ topv,
                             const int* __restrict__ pids,
                             const int* __restrict__ idxs,
                             const int* __restrict__ negsz,
                             float* __restrict__ out, int B) {
    __shared__ int pid_sh[256];
    __shared__ int mode_sh[16];
    __shared__ float red[256];
    int t = threadIdx.x;
    if (t < B) pid_sh[t] = pids[idxs[t]];
    __syncthreads();
    int half = B >> 1;
    int G = half / 16;
    if (t < G) {
        int bestPid = 0x7FFFFFFF, bestCnt = -1;
        for (int i = 0; i < 16; ++i) {
            int p = pid_sh[t * 16 + i];
            int c = 0;
            for (int j = 0; j < 16; ++j) c += (pid_sh[t * 16 + j] == p) ? 1 : 0;
            if (c > bestCnt || (c == bestCnt && p < bestPid)) { bestCnt = c; bestPid = p; }
        }
        mode_sh[t] = bestPid;  // ties -> smallest id == bincount().argmax()
    }
    __syncthreads();
    float contrib = 0.f;
    if (t < B) {
        int hb = (t < half) ? t : t - half;
        float mask = (pid_sh[hb] == mode_sh[hb / 16]) ? 1.f : 0.f;
        int ns = *negsz; if (ns > 32) ns = 32;
        float p20 = pos[t] * 20.0f;
        float m = p20;
        for (int j = 0; j < ns; ++j) m = fmaxf(m, topv[t * 32 + j] * 20.0f);
        float se = __expf(p20 - m);
        for (int j = 0; j < ns; ++j) se += __expf(topv[t * 32 + j] * 20.0f - m);
        float ce_neg = m + logf(se) - p20;
        float ce_main = logf(S[t]) - p20;
        contrib = (0.2f * mask * ce_neg + ce_main) / (float)B;
    }
    red[t] = contrib;
    __syncthreads();
    for (int s = 128; s > 0; s >>= 1) {
        if (t < s) red[t] += red[t + s];
        __syncthreads();
    }
    if (t == 0) out[0] = red[0];
}

// ---------- launcher ----------
extern "C" void kernel_launch(void* const* d_in, const int* in_sizes, int n_in,
                              void* d_out, int out_size, void* d_ws, size_t ws_size,
                              hipStream_t stream) {
    const float* inputs   = (const float*)d_in[0];
    const float* features = (const float*)d_in[1];
    const float* cents    = (const float*)d_in[2];
    const int*   targets  = (const int*)d_in[3];
    const int*   pids     = (const int*)d_in[4];
    const int*   idxs     = (const int*)d_in[5];
    const int*   negsz    = (const int*)d_in[6];
    float* out = (float*)d_out;

    int Bb = in_sizes[3];            // 256
    int Dd = in_sizes[0] / Bb;       // 2048
    int Nn = in_sizes[1] / Dd;       // 32768
    int Kk = in_sizes[2] / Dd;       // 8192

    char* ws = (char*)d_ws;
    unsigned short* xb = (unsigned short*)ws;
    size_t o = (size_t)Bb * Dd * 2;
    float* km   = (float*)(ws + o); o += (size_t)Bb * Kk * 4;
    float* S    = (float*)(ws + o); o += (size_t)Bb * 4;
    float* pos  = (float*)(ws + o); o += (size_t)Bb * 4;
    float* topv = (float*)(ws + o); o += (size_t)Bb * 32 * 4;

    norm_kernel<<<Bb, 256, 0, stream>>>(inputs, xb, S, Dd);
    int nbF = Nn / 64, nbC = Kk / 64;
    gemm_kernel<<<nbF + nbC, 256, 0, stream>>>(xb, features, cents, targets,
                                               S, pos, km, Dd, Kk, nbF);
    topk_kernel<<<Bb, 256, 0, stream>>>(km, pids, idxs, negsz, topv, Kk);
    final_kernel<<<1, 256, 0, stream>>>(S, pos, topv, pids, idxs, negsz, out, Bb);
}

// Round 4
// 611.106 us; speedup vs baseline: 1.0112x; 1.0112x over previous
//
#include <hip/hip_runtime.h>
#include <stdint.h>

typedef __attribute__((ext_vector_type(8))) short short8;
typedef __attribute__((ext_vector_type(4))) float floatx4;

// ---------- helpers ----------
__device__ __forceinline__ unsigned short f2b(float f) {
    union { float f; uint32_t u; } v; v.f = f;
    uint32_t u = v.u;
    return (unsigned short)((u + 0x7FFFu + ((u >> 16) & 1u)) >> 16);  // RNE
}

// pack two fp32 -> two bf16 (round-half-up; plenty of margin vs threshold)
__device__ __forceinline__ uint32_t pk2(float a, float b) {
    union { float f; uint32_t u; } x, y; x.f = a; y.f = b;
    uint32_t ua = x.u + 0x8000u, ub = y.u + 0x8000u;
    return (ua >> 16) | (ub & 0xFFFF0000u);
}

__device__ __forceinline__ void async16(const void* g, void* l) {
    __builtin_amdgcn_global_load_lds(
        (const __attribute__((address_space(1))) void*)g,
        (__attribute__((address_space(3))) void*)l, 16, 0, 0);
}

// ---------- kernel 1: L2-normalize rows, emit bf16; also zero S ----------
__global__ void norm_kernel(const float* __restrict__ in,
                            unsigned short* __restrict__ xb,
                            float* __restrict__ S, int D) {
    int b = blockIdx.x, t = threadIdx.x;
    if (t == 0) S[b] = 0.f;
    const float* row = in + (size_t)b * D;
    float ss = 0.f;
    for (int i = t * 4; i < D; i += 1024) {
        float4 v = *(const float4*)(row + i);
        ss += v.x * v.x + v.y * v.y + v.z * v.z + v.w * v.w;
    }
    for (int off = 32; off > 0; off >>= 1) ss += __shfl_down(ss, off);
    __shared__ float wsum[4];
    __shared__ float rn_sh;
    if ((t & 63) == 0) wsum[t >> 6] = ss;
    __syncthreads();
    if (t == 0) rn_sh = rsqrtf(wsum[0] + wsum[1] + wsum[2] + wsum[3]);
    __syncthreads();
    float rn = rn_sh;
    unsigned short* orow = xb + (size_t)b * D;
    for (int i = t * 4; i < D; i += 1024) {
        float4 v = *(const float4*)(row + i);
        ushort4 o;
        o.x = f2b(v.x * rn); o.y = f2b(v.y * rn);
        o.z = f2b(v.z * rn); o.w = f2b(v.w * rn);
        *(ushort4*)(orow + i) = o;
    }
}

// ---------- kernel 2: fused GEMM, dbuf DMA pipeline ----------
// BM=256 (full batch; B rows read from HBM exactly once), BN=32, BK=32.
// Grid = 1280 blocks -> 4 resident blocks/CU (LDS 40 KB), 16 waves/CU.
// Per iter: DMA-stage tile kt+1 into buf[p^1] (A bf16 from L2-resident xb,
// B fp32 from HBM), THEN compute tile kt from buf[p], THEN one barrier.
// The barrier's vmcnt(0) drain thus waits on loads issued a full compute
// phase earlier (R3 lesson: never put the drain right after issue).
// Swizzles (all LDS phases <=2-way = free; DMA dest lane-linear as required):
//   A row = 64 B, chunk g stored at slot g ^ ((R>>1)&3)
//   B row = 128 B (fp32), chunk c stored at slot c ^ (R&7)
// B is converted fp32->bf16 during fragment read (pk2), not in staging.
#define BKT 32
__global__ __launch_bounds__(256, 4)
void gemm_kernel(const unsigned short* __restrict__ xb,
                 const float* __restrict__ featB,
                 const float* __restrict__ centB,
                 const int* __restrict__ targets,
                 float* __restrict__ S, float* __restrict__ pos,
                 float* __restrict__ km,
                 int D, int K, int nbF) {
    __shared__ __align__(16) unsigned short Alds[2][256 * BKT];  // 2 x 16 KB
    __shared__ __align__(16) float Blds[2][32 * BKT];            // 2 x 4 KB

    const int t = threadIdx.x;
    const int w = t >> 6, l = t & 63;
    const int l15 = l & 15, g = l >> 4;
    const bool isFeat = ((int)blockIdx.x < nbF);
    const int n0 = (isFeat ? (int)blockIdx.x : ((int)blockIdx.x - nbF)) * 32;
    const float* Bsrc = isFeat ? featB : centB;
    const char* xbB = (const char*)xb;
    const char* BsB = (const char*)Bsrc;

    floatx4 acc[4][2];
#pragma unroll
    for (int ti = 0; ti < 4; ++ti)
#pragma unroll
        for (int tj = 0; tj < 2; ++tj)
            acc[ti][tj] = (floatx4){0.f, 0.f, 0.f, 0.f};

    const int kIters = D / BKT;                       // 64

    // staging index precompute
    const int ar = t >> 2;                            // A: 4 chunks/row
    const int acg = (t & 3) ^ ((ar >> 1) & 3);        // swizzled source chunk
    const int br = t >> 3;                            // B: 8 chunks/row
    const int bcg = (t & 7) ^ (br & 7);
    const size_t bRowByte = (size_t)(n0 + br) * (D * 4) + bcg * 16;

    auto stage = [&](int kt, int buf) {
        // A: 16 KB, 4 issues/thread, dest lane-linear
#pragma unroll
        for (int j = 0; j < 4; ++j) {
            int slin = j * 256 + t;
            int r = (j * 64) + ar;                    // slin>>2
            int cg = (t & 3) ^ ((r >> 1) & 3);
            async16(xbB + (size_t)r * (D * 2) + kt * 64 + cg * 16,
                    (char*)&Alds[buf][0] + slin * 16);
        }
        // B: 4 KB fp32, 1 issue/thread
        async16(BsB + bRowByte + kt * 128,
                (char*)&Blds[buf][0] + t * 16);
    };

    auto compute = [&](int buf) {
        short8 aF[4];
#pragma unroll
        for (int ti = 0; ti < 4; ++ti) {
            int R = w * 64 + ti * 16 + l15;
            aF[ti] = *(const short8*)((const char*)&Alds[buf][0] +
                      R * 64 + ((g ^ ((R >> 1) & 3)) * 16));
        }
        short8 bF[2];
#pragma unroll
        for (int tj = 0; tj < 2; ++tj) {
            int Rn = tj * 16 + l15;
            const char* bb = (const char*)&Blds[buf][0] + Rn * 128;
            float4 f0 = *(const float4*)(bb + (((2 * g) ^ (Rn & 7)) * 16));
            float4 f1 = *(const float4*)(bb + (((2 * g + 1) ^ (Rn & 7)) * 16));
            union { uint4 u; short8 s; } cv;
            cv.u.x = pk2(f0.x, f0.y); cv.u.y = pk2(f0.z, f0.w);
            cv.u.z = pk2(f1.x, f1.y); cv.u.w = pk2(f1.z, f1.w);
            bF[tj] = cv.s;
        }
#pragma unroll
        for (int ti = 0; ti < 4; ++ti)
#pragma unroll
            for (int tj = 0; tj < 2; ++tj)
                acc[ti][tj] = __builtin_amdgcn_mfma_f32_16x16x32_bf16(
                    aF[ti], bF[tj], acc[ti][tj], 0, 0, 0);
    };

    stage(0, 0);
    __syncthreads();
#pragma unroll 1
    for (int kt = 0; kt < kIters; ++kt) {
        int p = kt & 1;
        if (kt + 1 < kIters) stage(kt + 1, p ^ 1);
        compute(p);
        __syncthreads();
    }

    // epilogue.  C/D layout: col = l&15, row = (l>>4)*4 + reg  [m89-verified]
    if (isFeat) {
#pragma unroll
        for (int ti = 0; ti < 4; ++ti) {
#pragma unroll
            for (int r = 0; r < 4; ++r) {
                int row = w * 64 + ti * 16 + (g << 2) + r;
                int tr = targets[row];
                int col0 = n0 + l15;
                float e = 0.f;
#pragma unroll
                for (int tj = 0; tj < 2; ++tj) {
                    float c = acc[ti][tj][r];
                    e += __expf(c * 20.0f);            // |c|<=~1 -> safe
                    if (tr == col0 + tj * 16) pos[row] = c;
                }
                e += __shfl_xor(e, 1); e += __shfl_xor(e, 2);
                e += __shfl_xor(e, 4); e += __shfl_xor(e, 8);
                if (l15 == 0) atomicAdd(&S[row], e);
            }
        }
    } else {
#pragma unroll
        for (int ti = 0; ti < 4; ++ti) {
#pragma unroll
            for (int r = 0; r < 4; ++r) {
                int row = w * 64 + ti * 16 + (g << 2) + r;
                size_t base = (size_t)row * K + n0 + l15;
#pragma unroll
                for (int tj = 0; tj < 2; ++tj)
                    km[base + tj * 16] = acc[ti][tj][r];
            }
        }
    }
}

// ---------- kernel 3: per-row top-neg_size (register-resident selection) ----
__global__ __launch_bounds__(256, 4)
void topk_kernel(const float* __restrict__ kmr,
                 const int* __restrict__ pids,
                 const int* __restrict__ idxs,
                 const int* __restrict__ negsz,
                 float* __restrict__ topv, int K) {
    int b = blockIdx.x, t = threadIdx.x;
    int w = t >> 6, l = t & 63;
    const float* row = kmr + (size_t)b * K;
    float v[32];
#pragma unroll
    for (int k = 0; k < 32; ++k) v[k] = row[k * 256 + t];
    int gi = pids[idxs[b]];          // masked position (never top-20 in ref)
    if ((gi & 255) == t) {
        int kk = gi >> 8;
#pragma unroll
        for (int k = 0; k < 32; ++k) if (k == kk) v[k] = -1e30f;
    }
    float bv = v[0]; int bk = 0;
#pragma unroll
    for (int k = 1; k < 32; ++k) if (v[k] > bv) { bv = v[k]; bk = k; }

    __shared__ float rv[4];
    __shared__ int rg[4];
    int ns = *negsz; if (ns > 32) ns = 32;
    for (int j = 0; j < ns; ++j) {
        float mv = bv; int mg = bk * 256 + t;
#pragma unroll
        for (int off = 1; off < 64; off <<= 1) {
            float ov = __shfl_xor(mv, off);
            int og = __shfl_xor(mg, off);
            if (ov > mv) { mv = ov; mg = og; }
        }
        if (l == 0) { rv[w] = mv; rg[w] = mg; }
        __syncthreads();
        float gv = rv[0]; int gg = rg[0];
#pragma unroll
        for (int ww = 1; ww < 4; ++ww)
            if (rv[ww] > gv) { gv = rv[ww]; gg = rg[ww]; }
        if (t == 0) topv[b * 32 + j] = gv;
        if ((gg & 255) == t) {
            int kk = gg >> 8;
#pragma unroll
            for (int k = 0; k < 32; ++k) if (k == kk) v[k] = -1e30f;
            bv = v[0]; bk = 0;
#pragma unroll
            for (int k = 1; k < 32; ++k) if (v[k] > bv) { bv = v[k]; bk = k; }
        }
        __syncthreads();
    }
}

// ---------- kernel 4: confidence mask + losses + final scalar ----------
__global__ void final_kernel(const float* __restrict__ S,
                             const float* __restrict__ pos,
                             const float* __restrict__ topv,
                             const int* __restrict__ pids,
                             const int* __restrict__ idxs,
                             const int* __restrict__ negsz,
                             float* __restrict__ out, int B) {
    __shared__ int pid_sh[256];
    __shared__ int mode_sh[16];
    __shared__ float red[256];
    int t = threadIdx.x;
    if (t < B) pid_sh[t] = pids[idxs[t]];
    __syncthreads();
    int half = B >> 1;
    int G = half / 16;
    if (t < G) {
        int bestPid = 0x7FFFFFFF, bestCnt = -1;
        for (int i = 0; i < 16; ++i) {
            int p = pid_sh[t * 16 + i];
            int c = 0;
            for (int j = 0; j < 16; ++j) c += (pid_sh[t * 16 + j] == p) ? 1 : 0;
            if (c > bestCnt || (c == bestCnt && p < bestPid)) { bestCnt = c; bestPid = p; }
        }
        mode_sh[t] = bestPid;  // ties -> smallest id == bincount().argmax()
    }
    __syncthreads();
    float contrib = 0.f;
    if (t < B) {
        int hb = (t < half) ? t : t - half;
        float mask = (pid_sh[hb] == mode_sh[hb / 16]) ? 1.f : 0.f;
        int ns = *negsz; if (ns > 32) ns = 32;
        float p20 = pos[t] * 20.0f;
        float m = p20;
        for (int j = 0; j < ns; ++j) m = fmaxf(m, topv[t * 32 + j] * 20.0f);
        float se = __expf(p20 - m);
        for (int j = 0; j < ns; ++j) se += __expf(topv[t * 32 + j] * 20.0f - m);
        float ce_neg = m + logf(se) - p20;
        float ce_main = logf(S[t]) - p20;
        contrib = (0.2f * mask * ce_neg + ce_main) / (float)B;
    }
    red[t] = contrib;
    __syncthreads();
    for (int s = 128; s > 0; s >>= 1) {
        if (t < s) red[t] += red[t + s];
        __syncthreads();
    }
    if (t == 0) out[0] = red[0];
}

// ---------- launcher ----------
extern "C" void kernel_launch(void* const* d_in, const int* in_sizes, int n_in,
                              void* d_out, int out_size, void* d_ws, size_t ws_size,
                              hipStream_t stream) {
    const float* inputs   = (const float*)d_in[0];
    const float* features = (const float*)d_in[1];
    const float* cents    = (const float*)d_in[2];
    const int*   targets  = (const int*)d_in[3];
    const int*   pids     = (const int*)d_in[4];
    const int*   idxs     = (const int*)d_in[5];
    const int*   negsz    = (const int*)d_in[6];
    float* out = (float*)d_out;

    int Bb = in_sizes[3];            // 256
    int Dd = in_sizes[0] / Bb;       // 2048
    int Nn = in_sizes[1] / Dd;       // 32768
    int Kk = in_sizes[2] / Dd;       // 8192

    char* ws = (char*)d_ws;
    unsigned short* xb = (unsigned short*)ws;
    size_t o = (size_t)Bb * Dd * 2;
    float* km   = (float*)(ws + o); o += (size_t)Bb * Kk * 4;
    float* S    = (float*)(ws + o); o += (size_t)Bb * 4;
    float* pos  = (float*)(ws + o); o += (size_t)Bb * 4;
    float* topv = (float*)(ws + o); o += (size_t)Bb * 32 * 4;

    norm_kernel<<<Bb, 256, 0, stream>>>(inputs, xb, S, Dd);
    int nbF = Nn / 32, nbC = Kk / 32;
    gemm_kernel<<<nbF + nbC, 256, 0, stream>>>(xb, features, cents, targets,
                                               S, pos, km, Dd, Kk, nbF);
    topk_kernel<<<Bb, 256, 0, stream>>>(km, pids, idxs, negsz, topv, Kk);
    final_kernel<<<1, 256, 0, stream>>>(S, pos, topv, pids, idxs, negsz, out, Bb);
}